// Round 5
// baseline (1803.885 us; speedup 1.0000x reference)
//
#include <hip/hip_runtime.h>
#include <stdint.h>

#define DEV __device__ __forceinline__

constexpr int E_ = 16, M_ = 128, H_ = 2048, I_ = 2048;
constexpr int X_ = 16;            // A*B = 2*8
constexpr int N1 = 2 * I_;        // 4096
constexpr int ROWS = X_ * M_;     // 2048 rows per expert

typedef short bfrag __attribute__((ext_vector_type(8)));   // 8 bf16 (4 VGPRs)
typedef float ffrag __attribute__((ext_vector_type(4)));   // MFMA C/D frag
typedef unsigned short us8 __attribute__((ext_vector_type(8)));

DEV unsigned short f2bf(float f) {
    union { float f; unsigned u; } v; v.f = f;
    unsigned u = v.u;
    u += 0x7fffu + ((u >> 16) & 1u);   // RNE
    return (unsigned short)(u >> 16);
}

DEV void gload16(const void* g, void* lds_wave_base) {
    __builtin_amdgcn_global_load_lds(
        (const __attribute__((address_space(1))) unsigned int*)g,
        (__attribute__((address_space(3))) unsigned int*)lds_wave_base,
        16, 0, 0);
}

DEV void block_bar() {
    asm volatile("" ::: "memory");
    __builtin_amdgcn_s_barrier();
    asm volatile("" ::: "memory");
}

// ---------------- converts ----------------

// dispatched (X,E,M,H) f32 -> a_bf (E, X*M, H) bf16  (token-major per expert)
__global__ __launch_bounds__(256) void convert_a(const float* __restrict__ in,
                                                 unsigned short* __restrict__ outb) {
    const int n4 = X_ * E_ * M_ * H_ / 4;
    int idx = blockIdx.x * 256 + threadIdx.x;
    int stride = gridDim.x * 256;
    for (int f = idx; f < n4; f += stride) {
        float4 v = ((const float4*)in)[f];
        ushort4 o;
        o.x = f2bf(v.x); o.y = f2bf(v.y); o.z = f2bf(v.z); o.w = f2bf(v.w);
        const int c = f & 511;          // float4 within row (H/4 = 512)
        const int row = f >> 9;         // (x,e,m) row
        const int m = row & 127, e = (row >> 7) & 15, x = row >> 11;
        ((ushort4*)outb)[((size_t)(e * ROWS + x * M_ + m) << 9) + c] = o;
    }
}

// gate_up (E,H,4096) fp32 -> b1t (E,4096,H) bf16, de-interleaved
__global__ __launch_bounds__(256) void convert_b1(const float* __restrict__ gup,
                                                  unsigned short* __restrict__ b1t) {
    const int e = blockIdx.x, h0 = blockIdx.y * 64, n0 = blockIdx.z * 128;
    __shared__ float tile[64][129];
    const float* src = gup + (size_t)e * H_ * N1;
    const int t = threadIdx.x;
#pragma unroll
    for (int i = 0; i < 8; ++i) {
        int idx = i * 1024 + t * 4;
        int r = idx >> 7, c = idx & 127;
        float4 v = *(const float4*)(src + (size_t)(h0 + r) * N1 + n0 + c);
        tile[r][c] = v.x; tile[r][c + 1] = v.y; tile[r][c + 2] = v.z; tile[r][c + 3] = v.w;
    }
    __syncthreads();
    const int p = t >> 2;
    const int hh = (t & 3) * 16;
    us8 g0, g1, u0, u1;
#pragma unroll
    for (int k = 0; k < 8; ++k) {
        g0[k] = f2bf(tile[hh + k][2 * p]);
        u0[k] = f2bf(tile[hh + k][2 * p + 1]);
        g1[k] = f2bf(tile[hh + 8 + k][2 * p]);
        u1[k] = f2bf(tile[hh + 8 + k][2 * p + 1]);
    }
    unsigned short* dg = b1t + ((size_t)e * N1 + (n0 >> 1) + p) * H_ + h0 + hh;
    unsigned short* du = b1t + ((size_t)e * N1 + I_ + (n0 >> 1) + p) * H_ + h0 + hh;
    *(us8*)dg = g0; *(us8*)(dg + 8) = g1;
    *(us8*)du = u0; *(us8*)(du + 8) = u1;
}

// down (E,I,H) fp32 -> b2t (E,H,I) bf16
__global__ __launch_bounds__(256) void convert_b2(const float* __restrict__ dwn,
                                                  unsigned short* __restrict__ b2t) {
    const int e = blockIdx.x, i0 = blockIdx.y * 64, h0 = blockIdx.z * 64;
    __shared__ float tile[64][65];
    const float* src = dwn + (size_t)e * I_ * H_;
    const int t = threadIdx.x;
#pragma unroll
    for (int it = 0; it < 4; ++it) {
        int idx = it * 1024 + t * 4;
        int r = idx >> 6, c = idx & 63;
        float4 v = *(const float4*)(src + (size_t)(i0 + r) * H_ + h0 + c);
        tile[r][c] = v.x; tile[r][c + 1] = v.y; tile[r][c + 2] = v.z; tile[r][c + 3] = v.w;
    }
    __syncthreads();
    const int hl = t >> 2, ii = (t & 3) * 16;
    us8 o0, o1;
#pragma unroll
    for (int k = 0; k < 8; ++k) {
        o0[k] = f2bf(tile[ii + k][hl]);
        o1[k] = f2bf(tile[ii + 8 + k][hl]);
    }
    unsigned short* d = b2t + ((size_t)e * H_ + h0 + hl) * I_ + i0 + ii;
    *(us8*)d = o0; *(us8*)(d + 8) = o1;
}

// ---------------- 256x256 8-wave deep-pipelined GEMM ----------------
// MODE 0: gemm1 (gate_up + GLU epilogue); MODE 1: gemm2 (down proj + bias).
//
// BM=BN=256, BK=64, 8 waves (2M x 4N), per-wave output 128x64.
// LDS: 2 K-tile double buffer x (A 32KB + B 32KB) = 128 KB.
// Per K-tile: ONLY 2 barriers (publish after per-wave vmcnt(8); retire at
// end). Inside the tile, fragment reads are pipelined with counted
// lgkmcnt so each wave's LDS drain hides under its own (and, with waves
// free-running between barriers, other waves') MFMA bursts:
//   issue B0(4) A0(8) B1(4) -> lgkm(4) -> 16 MFMA (mh0 nh0)
//   issue A1(8)             -> lgkm(8) -> 16 MFMA (mh0 nh1)
//                           -> lgkm(0) -> 32 MFMA (mh1 nh1 + mh1 nh0)
// 24 ds_read_b128/wave/K-tile (data floor); B frags resident all tile.
template <int MODE>
__global__ __launch_bounds__(512, 2) void gemm8p(
    const unsigned short* __restrict__ A,   // (E,2048,2048) bf16
    const unsigned short* __restrict__ B,   // MODE0: (E,4096,2048); MODE1: (E,2048,2048)
    const float* __restrict__ bias,         // MODE0: (E,4096) interleaved; MODE1: (E,2048)
    void* __restrict__ outv)                // MODE0: act bf16 (E,2048,2048); MODE1: f32 (2048,16,2048)
{
    constexpr int LD = 2048;
    constexpr int NT = 2048 / 64;           // 32 K-tiles

    __shared__ unsigned short lds[2][2][256 * 64];   // [buf][A/B][row*64+k]

    const int t = threadIdx.x, wave = t >> 6, lane = t & 63;
    const int wr = wave >> 2, wc = wave & 3;         // 2M x 4N

    // XCD-aware bijective swizzle (nwg % 8 == 0 for both modes)
    int id = blockIdx.x;
    const int cpx = gridDim.x >> 3;
    id = (id & 7) * cpx + (id >> 3);
    int e, mt, bt;
    if (MODE == 0) { e = id >> 7; mt = (id >> 4) & 7; bt = id & 15; }
    else           { e = id >> 6; mt = (id >> 3) & 7; bt = id & 7; }

    const unsigned short* Aexp = A + ((size_t)e * ROWS + mt * 256) * LD;
    const unsigned short* Bexp = (MODE == 0)
        ? B + (size_t)e * N1 * LD
        : B + ((size_t)e * H_ + bt * 256) * LD;

    ffrag acc[8][4];
#pragma unroll
    for (int i = 0; i < 8; ++i)
#pragma unroll
        for (int j = 0; j < 4; ++j) acc[i][j] = ffrag{0.f, 0.f, 0.f, 0.f};

    const int rsub = lane >> 3;
    const int csw = ((lane & 7) ^ (lane >> 3)) * 8;  // inverse-swizzled k-chunk (elements)

    auto stage = [&](int kt, int b) {
        const int k0 = kt * 64;
#pragma unroll
        for (int i = 0; i < 4; ++i) {
            const int Rb = (wave * 4 + i) * 8;
            const int r = Rb + rsub;
            gload16(Aexp + (size_t)r * LD + k0 + csw, (void*)&lds[b][0][Rb * 64]);
        }
#pragma unroll
        for (int i = 0; i < 4; ++i) {
            const int Rb = (wave * 4 + i) * 8;
            const int r = Rb + rsub;
            int grow;
            if (MODE == 0)
                grow = ((r >> 5) & 1) * I_ + bt * 128 + (r >> 6) * 32 + (r & 31);
            else
                grow = r;
            gload16(Bexp + (size_t)grow * LD + k0 + csw, (void*)&lds[b][1][Rb * 64]);
        }
    };

    stage(0, 0);

    const int l15 = lane & 15, lr16 = lane >> 4, sw = lane & 7;
    const int arow0 = wr * 128 + l15;       // A row base for this wave/lane
    const int brow0 = wc * 64 + l15;        // B row base

#pragma unroll 2
    for (int kt = 0; kt < NT; ++kt) {
        const int cur = kt & 1;
        if (kt + 1 < NT) {
            stage(kt + 1, cur ^ 1);
            __builtin_amdgcn_sched_barrier(0);
            asm volatile("s_waitcnt vmcnt(8)" ::: "memory");
        } else {
            asm volatile("s_waitcnt vmcnt(0)" ::: "memory");
        }
        __builtin_amdgcn_sched_barrier(0);
        block_bar();   // publish buf[cur] (all waves' stage loads landed)

        bfrag bB0[2][2], bB1[2][2];   // B resident for whole K-tile
        bfrag af0[4][2], af1[4][2];   // A halves, pipelined

        // issue group 1: B0 (4) + A0 (8)
#pragma unroll
        for (int nf = 0; nf < 2; ++nf)
#pragma unroll
            for (int ks = 0; ks < 2; ++ks)
                bB0[nf][ks] = *(const bfrag*)&lds[cur][1][(brow0 + nf * 16) * 64 + (((ks * 4 + lr16) ^ sw) * 8)];
#pragma unroll
        for (int mf = 0; mf < 4; ++mf)
#pragma unroll
            for (int ks = 0; ks < 2; ++ks)
                af0[mf][ks] = *(const bfrag*)&lds[cur][0][(arow0 + mf * 16) * 64 + (((ks * 4 + lr16) ^ sw) * 8)];
        asm volatile("" ::: "memory");   // pin FIFO order of read groups
        // issue group 2: B1 (4)
#pragma unroll
        for (int nf = 0; nf < 2; ++nf)
#pragma unroll
            for (int ks = 0; ks < 2; ++ks)
                bB1[nf][ks] = *(const bfrag*)&lds[cur][1][(brow0 + 32 + nf * 16) * 64 + (((ks * 4 + lr16) ^ sw) * 8)];

        // wait group 1 (4 outstanding = B1), then MFMA block0 (mh0, nh0)
        asm volatile("s_waitcnt lgkmcnt(4)" ::: "memory");
        __builtin_amdgcn_sched_barrier(0);
        __builtin_amdgcn_s_setprio(1);
#pragma unroll
        for (int mf = 0; mf < 4; ++mf)
#pragma unroll
            for (int nf = 0; nf < 2; ++nf)
#pragma unroll
                for (int ks = 0; ks < 2; ++ks)
                    acc[mf][nf] = __builtin_amdgcn_mfma_f32_16x16x32_bf16(
                        af0[mf][ks], bB0[nf][ks], acc[mf][nf], 0, 0, 0);
        __builtin_amdgcn_s_setprio(0);

        // issue group 3: A1 (8)
#pragma unroll
        for (int mf = 0; mf < 4; ++mf)
#pragma unroll
            for (int ks = 0; ks < 2; ++ks)
                af1[mf][ks] = *(const bfrag*)&lds[cur][0][(arow0 + 64 + mf * 16) * 64 + (((ks * 4 + lr16) ^ sw) * 8)];

        // wait group 2 (8 outstanding = A1), MFMA block1 (mh0, nh1)
        asm volatile("s_waitcnt lgkmcnt(8)" ::: "memory");
        __builtin_amdgcn_sched_barrier(0);
        __builtin_amdgcn_s_setprio(1);
#pragma unroll
        for (int mf = 0; mf < 4; ++mf)
#pragma unroll
            for (int nf = 0; nf < 2; ++nf)
#pragma unroll
                for (int ks = 0; ks < 2; ++ks)
                    acc[mf][2 + nf] = __builtin_amdgcn_mfma_f32_16x16x32_bf16(
                        af0[mf][ks], bB1[nf][ks], acc[mf][2 + nf], 0, 0, 0);
        __builtin_amdgcn_s_setprio(0);

        // wait group 3, MFMA blocks 2+3 (mh1, nh1) + (mh1, nh0)
        asm volatile("s_waitcnt lgkmcnt(0)" ::: "memory");
        __builtin_amdgcn_sched_barrier(0);
        __builtin_amdgcn_s_setprio(1);
#pragma unroll
        for (int mf = 0; mf < 4; ++mf)
#pragma unroll
            for (int nf = 0; nf < 2; ++nf)
#pragma unroll
                for (int ks = 0; ks < 2; ++ks)
                    acc[4 + mf][2 + nf] = __builtin_amdgcn_mfma_f32_16x16x32_bf16(
                        af1[mf][ks], bB1[nf][ks], acc[4 + mf][2 + nf], 0, 0, 0);
#pragma unroll
        for (int mf = 0; mf < 4; ++mf)
#pragma unroll
            for (int nf = 0; nf < 2; ++nf)
#pragma unroll
                for (int ks = 0; ks < 2; ++ks)
                    acc[4 + mf][nf] = __builtin_amdgcn_mfma_f32_16x16x32_bf16(
                        af1[mf][ks], bB0[nf][ks], acc[4 + mf][nf], 0, 0, 0);
        __builtin_amdgcn_s_setprio(0);

        block_bar();   // retire buf[cur] (safe to overwrite next tile)
    }

    // -------- epilogue --------
    const int rb = mt * 256 + wr * 128 + lr16 * 4;
    if (MODE == 0) {
        unsigned short* act = (unsigned short*)outv + (size_t)e * ROWS * I_;
#pragma unroll
        for (int nf = 0; nf < 2; ++nf) {
            const int jj = bt * 128 + wc * 32 + nf * 16 + l15;
            const float gb = bias[(size_t)e * N1 + 2 * jj];
            const float ub = bias[(size_t)e * N1 + 2 * jj + 1];
#pragma unroll
            for (int mf = 0; mf < 8; ++mf)
#pragma unroll
                for (int r = 0; r < 4; ++r) {
                    float g = acc[mf][nf][r] + gb;
                    float u = acc[mf][2 + nf][r] + ub;
                    g = fminf(g, 7.0f);
                    u = fminf(fmaxf(u, -7.0f), 7.0f);
                    const float glu = g / (1.0f + __expf(-1.702f * g));
                    const float av = (u + 1.0f) * glu;
                    act[(size_t)(rb + mf * 16 + r) * I_ + jj] = f2bf(av);
                }
        }
    } else {
        float* out = (float*)outv;
#pragma unroll
        for (int nf = 0; nf < 4; ++nf) {
            const int h = bt * 256 + wc * 64 + nf * 16 + l15;
            const float bb = bias[(size_t)e * H_ + h];
#pragma unroll
            for (int mf = 0; mf < 8; ++mf)
#pragma unroll
                for (int r = 0; r < 4; ++r) {
                    const int row = rb + mf * 16 + r;
                    out[((size_t)row * E_ + e) * H_ + h] = acc[mf][nf][r] + bb;
                }
        }
    }
}

// ---------------- launch ----------------

extern "C" void kernel_launch(void* const* d_in, const int* in_sizes, int n_in,
                              void* d_out, int out_size, void* d_ws, size_t ws_size,
                              hipStream_t stream) {
    const float* disp  = (const float*)d_in[0];
    const float* gup   = (const float*)d_in[1];
    const float* gub   = (const float*)d_in[2];
    const float* down  = (const float*)d_in[3];
    const float* dbias = (const float*)d_in[4];
    float* out = (float*)d_out;

    const size_t NEED = (size_t)512 << 20;
    if (ws_size < NEED) {
        hipMemsetAsync(d_out, 0, (size_t)out_size * sizeof(float), stream);
        return;
    }
    unsigned short* a_bf = (unsigned short*)d_ws;
    unsigned short* b1t  = (unsigned short*)((char*)d_ws + ((size_t)128 << 20));
    unsigned short* b2t  = b1t;  // reused after gemm1 (stream-ordered)
    unsigned short* actb = (unsigned short*)((char*)d_ws + ((size_t)384 << 20));

    convert_a<<<4096, 256, 0, stream>>>(disp, a_bf);
    convert_b1<<<dim3(E_, H_ / 64, N1 / 128), 256, 0, stream>>>(gup, b1t);
    gemm8p<0><<<2048, 512, 0, stream>>>(a_bf, b1t, gub, actb);
    convert_b2<<<dim3(E_, I_ / 64, H_ / 64), 256, 0, stream>>>(down, b2t);
    gemm8p<1><<<1024, 512, 0, stream>>>(actb, b2t, dbias, out);
}

// Round 6
// 1107.755 us; speedup vs baseline: 1.6284x; 1.6284x over previous
//
#include <hip/hip_runtime.h>
#include <stdint.h>

#define DEV __device__ __forceinline__

constexpr int E_ = 16, M_ = 128, H_ = 2048, I_ = 2048;
constexpr int X_ = 16;            // A*B = 2*8
constexpr int N1 = 2 * I_;        // 4096
constexpr int ROWS = X_ * M_;     // 2048 rows per expert

typedef short bfrag __attribute__((ext_vector_type(8)));   // 8 bf16 (4 VGPRs)
typedef float ffrag __attribute__((ext_vector_type(4)));   // MFMA C/D frag
typedef unsigned short us8 __attribute__((ext_vector_type(8)));

DEV unsigned short f2bf(float f) {
    union { float f; unsigned u; } v; v.f = f;
    unsigned u = v.u;
    u += 0x7fffu + ((u >> 16) & 1u);   // RNE
    return (unsigned short)(u >> 16);
}

DEV void gload16(const void* g, void* lds_wave_base) {
    __builtin_amdgcn_global_load_lds(
        (const __attribute__((address_space(1))) unsigned int*)g,
        (__attribute__((address_space(3))) unsigned int*)lds_wave_base,
        16, 0, 0);
}

DEV void block_bar() {
    asm volatile("" ::: "memory");
    __builtin_amdgcn_s_barrier();
    asm volatile("" ::: "memory");
}

// ---------------- converts ----------------

// dispatched (X,E,M,H) f32 -> a_bf (E, X*M, H) bf16  (token-major per expert)
__global__ __launch_bounds__(256) void convert_a(const float* __restrict__ in,
                                                 unsigned short* __restrict__ outb) {
    const int n4 = X_ * E_ * M_ * H_ / 4;
    int idx = blockIdx.x * 256 + threadIdx.x;
    int stride = gridDim.x * 256;
    for (int f = idx; f < n4; f += stride) {
        float4 v = ((const float4*)in)[f];
        ushort4 o;
        o.x = f2bf(v.x); o.y = f2bf(v.y); o.z = f2bf(v.z); o.w = f2bf(v.w);
        const int c = f & 511;          // float4 within row (H/4 = 512)
        const int row = f >> 9;         // (x,e,m) row
        const int m = row & 127, e = (row >> 7) & 15, x = row >> 11;
        ((ushort4*)outb)[((size_t)(e * ROWS + x * M_ + m) << 9) + c] = o;
    }
}

// gate_up (E,H,4096) fp32 -> b1t (E,4096,H) bf16, de-interleaved
__global__ __launch_bounds__(256) void convert_b1(const float* __restrict__ gup,
                                                  unsigned short* __restrict__ b1t) {
    const int e = blockIdx.x, h0 = blockIdx.y * 64, n0 = blockIdx.z * 128;
    __shared__ float tile[64][129];
    const float* src = gup + (size_t)e * H_ * N1;
    const int t = threadIdx.x;
#pragma unroll
    for (int i = 0; i < 8; ++i) {
        int idx = i * 1024 + t * 4;
        int r = idx >> 7, c = idx & 127;
        float4 v = *(const float4*)(src + (size_t)(h0 + r) * N1 + n0 + c);
        tile[r][c] = v.x; tile[r][c + 1] = v.y; tile[r][c + 2] = v.z; tile[r][c + 3] = v.w;
    }
    __syncthreads();
    const int p = t >> 2;
    const int hh = (t & 3) * 16;
    us8 g0, g1, u0, u1;
#pragma unroll
    for (int k = 0; k < 8; ++k) {
        g0[k] = f2bf(tile[hh + k][2 * p]);
        u0[k] = f2bf(tile[hh + k][2 * p + 1]);
        g1[k] = f2bf(tile[hh + 8 + k][2 * p]);
        u1[k] = f2bf(tile[hh + 8 + k][2 * p + 1]);
    }
    unsigned short* dg = b1t + ((size_t)e * N1 + (n0 >> 1) + p) * H_ + h0 + hh;
    unsigned short* du = b1t + ((size_t)e * N1 + I_ + (n0 >> 1) + p) * H_ + h0 + hh;
    *(us8*)dg = g0; *(us8*)(dg + 8) = g1;
    *(us8*)du = u0; *(us8*)(du + 8) = u1;
}

// down (E,I,H) fp32 -> b2t (E,H,I) bf16
__global__ __launch_bounds__(256) void convert_b2(const float* __restrict__ dwn,
                                                  unsigned short* __restrict__ b2t) {
    const int e = blockIdx.x, i0 = blockIdx.y * 64, h0 = blockIdx.z * 64;
    __shared__ float tile[64][65];
    const float* src = dwn + (size_t)e * I_ * H_;
    const int t = threadIdx.x;
#pragma unroll
    for (int it = 0; it < 4; ++it) {
        int idx = it * 1024 + t * 4;
        int r = idx >> 6, c = idx & 63;
        float4 v = *(const float4*)(src + (size_t)(i0 + r) * H_ + h0 + c);
        tile[r][c] = v.x; tile[r][c + 1] = v.y; tile[r][c + 2] = v.z; tile[r][c + 3] = v.w;
    }
    __syncthreads();
    const int hl = t >> 2, ii = (t & 3) * 16;
    us8 o0, o1;
#pragma unroll
    for (int k = 0; k < 8; ++k) {
        o0[k] = f2bf(tile[ii + k][hl]);
        o1[k] = f2bf(tile[ii + 8 + k][hl]);
    }
    unsigned short* d = b2t + ((size_t)e * H_ + h0 + hl) * I_ + i0 + ii;
    *(us8*)d = o0; *(us8*)(d + 8) = o1;
}

// ---------------- 256x256 8-wave deep-pipelined GEMM ----------------
// MODE 0: gemm1 (gate_up + GLU epilogue); MODE 1: gemm2 (down proj + bias).
//
// BM=BN=256, BK=64, 8 waves (2M x 4N), per-wave output 128x64.
// LDS: 2 K-tile double buffer x (A 32KB + B 32KB) = 128 KB.
//
// ONE barrier per K-tile; per-wave counted lgkm waits overlap each wave's
// LDS drain with other waves' MFMA bursts (waves free-run inside a tile).
// Safety: a wave reaches the tile barrier only after lgkm-completing all
// its reads of the old buffer, so post-barrier stage writes into it are
// safe; vmcnt(0) at tile top drains loads issued mid-previous-tile (free).
// Register budget = round-3's proven 48 frag VGPRs (A1 re-reads into a
// fresh name after af dies) — round-4's 64 spilled to scratch.
template <int MODE>
__global__ __launch_bounds__(512, 2) void gemm8p(
    const unsigned short* __restrict__ A,   // (E,2048,2048) bf16
    const unsigned short* __restrict__ B,   // MODE0: (E,4096,2048); MODE1: (E,2048,2048)
    const float* __restrict__ bias,         // MODE0: (E,4096) interleaved; MODE1: (E,2048)
    void* __restrict__ outv)                // MODE0: act bf16 (E,2048,2048); MODE1: f32 (2048,16,2048)
{
    constexpr int LD = 2048;
    constexpr int NT = 2048 / 64;           // 32 K-tiles

    __shared__ unsigned short lds[2][2][256 * 64];   // [buf][A/B][row*64+k]

    const int t = threadIdx.x, wave = t >> 6, lane = t & 63;
    const int wr = wave >> 2, wc = wave & 3;         // 2M x 4N

    // XCD-aware bijective swizzle (nwg % 8 == 0 for both modes)
    int id = blockIdx.x;
    const int cpx = gridDim.x >> 3;
    id = (id & 7) * cpx + (id >> 3);
    int e, mt, bt;
    if (MODE == 0) { e = id >> 7; mt = (id >> 4) & 7; bt = id & 15; }
    else           { e = id >> 6; mt = (id >> 3) & 7; bt = id & 7; }

    const unsigned short* Aexp = A + ((size_t)e * ROWS + mt * 256) * LD;
    const unsigned short* Bexp = (MODE == 0)
        ? B + (size_t)e * N1 * LD
        : B + ((size_t)e * H_ + bt * 256) * LD;

    ffrag acc[8][4];
#pragma unroll
    for (int i = 0; i < 8; ++i)
#pragma unroll
        for (int j = 0; j < 4; ++j) acc[i][j] = ffrag{0.f, 0.f, 0.f, 0.f};

    const int rsub = lane >> 3;
    const int csw = ((lane & 7) ^ (lane >> 3)) * 8;  // inverse-swizzled k-chunk (elements)

    auto stage = [&](int kt, int b) {
        const int k0 = kt * 64;
#pragma unroll
        for (int i = 0; i < 4; ++i) {
            const int Rb = (wave * 4 + i) * 8;
            const int r = Rb + rsub;
            gload16(Aexp + (size_t)r * LD + k0 + csw, (void*)&lds[b][0][Rb * 64]);
        }
#pragma unroll
        for (int i = 0; i < 4; ++i) {
            const int Rb = (wave * 4 + i) * 8;
            const int r = Rb + rsub;
            int grow;
            if (MODE == 0)
                grow = ((r >> 5) & 1) * I_ + bt * 128 + (r >> 6) * 32 + (r & 31);
            else
                grow = r;
            gload16(Bexp + (size_t)grow * LD + k0 + csw, (void*)&lds[b][1][Rb * 64]);
        }
    };

    stage(0, 0);

    const int l15 = lane & 15, lr16 = lane >> 4, sw = lane & 7;
    const int arow0 = wr * 128 + l15;       // A row base for this wave/lane
    const int brow0 = wc * 64 + l15;        // B row base

#pragma unroll 2
    for (int kt = 0; kt < NT; ++kt) {
        const int cur = kt & 1;

        // drain this tile's stage loads (issued mid-previous-tile -> old -> ~free)
        asm volatile("s_waitcnt vmcnt(0)" ::: "memory");
        __builtin_amdgcn_sched_barrier(0);
        block_bar();   // publish buf[cur]; old buffer's reads all retired

        bfrag bB0[2][2], bB1[2][2];
        bfrag af[4][2];

        // issue reads: B0 (4), A0 (8), B1 (4)  -> 16 outstanding
#pragma unroll
        for (int nf = 0; nf < 2; ++nf)
#pragma unroll
            for (int ks = 0; ks < 2; ++ks)
                bB0[nf][ks] = *(const bfrag*)&lds[cur][1][(brow0 + nf * 16) * 64 + (((ks * 4 + lr16) ^ sw) * 8)];
#pragma unroll
        for (int mf = 0; mf < 4; ++mf)
#pragma unroll
            for (int ks = 0; ks < 2; ++ks)
                af[mf][ks] = *(const bfrag*)&lds[cur][0][(arow0 + mf * 16) * 64 + (((ks * 4 + lr16) ^ sw) * 8)];
        asm volatile("" ::: "memory");   // pin FIFO order
#pragma unroll
        for (int nf = 0; nf < 2; ++nf)
#pragma unroll
            for (int ks = 0; ks < 2; ++ks)
                bB1[nf][ks] = *(const bfrag*)&lds[cur][1][(brow0 + 32 + nf * 16) * 64 + (((ks * 4 + lr16) ^ sw) * 8)];

        // prefetch next tile into the other buffer (safe: post-barrier)
        if (kt + 1 < NT) stage(kt + 1, cur ^ 1);

        // MFMA block0 (mh0,nh0): needs B0+A0 -> allow B1's 4 outstanding
        asm volatile("s_waitcnt lgkmcnt(4)" ::: "memory");
        __builtin_amdgcn_sched_barrier(0);
        __builtin_amdgcn_s_setprio(1);
#pragma unroll
        for (int mf = 0; mf < 4; ++mf)
#pragma unroll
            for (int nf = 0; nf < 2; ++nf)
#pragma unroll
                for (int ks = 0; ks < 2; ++ks)
                    acc[mf][nf] = __builtin_amdgcn_mfma_f32_16x16x32_bf16(
                        af[mf][ks], bB0[nf][ks], acc[mf][nf], 0, 0, 0);
        __builtin_amdgcn_s_setprio(0);

        // MFMA block1 (mh0,nh1)
        asm volatile("s_waitcnt lgkmcnt(0)" ::: "memory");
        __builtin_amdgcn_sched_barrier(0);
        __builtin_amdgcn_s_setprio(1);
#pragma unroll
        for (int mf = 0; mf < 4; ++mf)
#pragma unroll
            for (int nf = 0; nf < 2; ++nf)
#pragma unroll
                for (int ks = 0; ks < 2; ++ks)
                    acc[mf][2 + nf] = __builtin_amdgcn_mfma_f32_16x16x32_bf16(
                        af[mf][ks], bB1[nf][ks], acc[mf][2 + nf], 0, 0, 0);
        __builtin_amdgcn_s_setprio(0);

        // A1 reads into a fresh frag (af dead -> same budget as round 3)
        bfrag ag[4][2];
#pragma unroll
        for (int mf = 0; mf < 4; ++mf)
#pragma unroll
            for (int ks = 0; ks < 2; ++ks)
                ag[mf][ks] = *(const bfrag*)&lds[cur][0][(arow0 + 64 + mf * 16) * 64 + (((ks * 4 + lr16) ^ sw) * 8)];

        // MFMA blocks 2+3 (mh1,nh1) + (mh1,nh0)
        asm volatile("s_waitcnt lgkmcnt(0)" ::: "memory");
        __builtin_amdgcn_sched_barrier(0);
        __builtin_amdgcn_s_setprio(1);
#pragma unroll
        for (int mf = 0; mf < 4; ++mf)
#pragma unroll
            for (int nf = 0; nf < 2; ++nf)
#pragma unroll
                for (int ks = 0; ks < 2; ++ks)
                    acc[4 + mf][2 + nf] = __builtin_amdgcn_mfma_f32_16x16x32_bf16(
                        ag[mf][ks], bB1[nf][ks], acc[4 + mf][2 + nf], 0, 0, 0);
#pragma unroll
        for (int mf = 0; mf < 4; ++mf)
#pragma unroll
            for (int nf = 0; nf < 2; ++nf)
#pragma unroll
                for (int ks = 0; ks < 2; ++ks)
                    acc[4 + mf][nf] = __builtin_amdgcn_mfma_f32_16x16x32_bf16(
                        ag[mf][ks], bB0[nf][ks], acc[4 + mf][nf], 0, 0, 0);
        __builtin_amdgcn_s_setprio(0);
        // no trailing barrier: next tile's top barrier provides it
    }

    // -------- epilogue --------
    const int rb = mt * 256 + wr * 128 + lr16 * 4;
    if (MODE == 0) {
        unsigned short* act = (unsigned short*)outv + (size_t)e * ROWS * I_;
#pragma unroll
        for (int nf = 0; nf < 2; ++nf) {
            const int jj = bt * 128 + wc * 32 + nf * 16 + l15;
            const float gb = bias[(size_t)e * N1 + 2 * jj];
            const float ub = bias[(size_t)e * N1 + 2 * jj + 1];
#pragma unroll
            for (int mf = 0; mf < 8; ++mf)
#pragma unroll
                for (int r = 0; r < 4; ++r) {
                    float g = acc[mf][nf][r] + gb;
                    float u = acc[mf][2 + nf][r] + ub;
                    g = fminf(g, 7.0f);
                    u = fminf(fmaxf(u, -7.0f), 7.0f);
                    const float glu = g / (1.0f + __expf(-1.702f * g));
                    const float av = (u + 1.0f) * glu;
                    act[(size_t)(rb + mf * 16 + r) * I_ + jj] = f2bf(av);
                }
        }
    } else {
        float* out = (float*)outv;
#pragma unroll
        for (int nf = 0; nf < 4; ++nf) {
            const int h = bt * 256 + wc * 64 + nf * 16 + l15;
            const float bb = bias[(size_t)e * H_ + h];
#pragma unroll
            for (int mf = 0; mf < 8; ++mf)
#pragma unroll
                for (int r = 0; r < 4; ++r) {
                    const int row = rb + mf * 16 + r;
                    out[((size_t)row * E_ + e) * H_ + h] = acc[mf][nf][r] + bb;
                }
        }
    }
}

// ---------------- launch ----------------

extern "C" void kernel_launch(void* const* d_in, const int* in_sizes, int n_in,
                              void* d_out, int out_size, void* d_ws, size_t ws_size,
                              hipStream_t stream) {
    const float* disp  = (const float*)d_in[0];
    const float* gup   = (const float*)d_in[1];
    const float* gub   = (const float*)d_in[2];
    const float* down  = (const float*)d_in[3];
    const float* dbias = (const float*)d_in[4];
    float* out = (float*)d_out;

    const size_t NEED = (size_t)512 << 20;
    if (ws_size < NEED) {
        hipMemsetAsync(d_out, 0, (size_t)out_size * sizeof(float), stream);
        return;
    }
    unsigned short* a_bf = (unsigned short*)d_ws;
    unsigned short* b1t  = (unsigned short*)((char*)d_ws + ((size_t)128 << 20));
    unsigned short* b2t  = b1t;  // reused after gemm1 (stream-ordered)
    unsigned short* actb = (unsigned short*)((char*)d_ws + ((size_t)384 << 20));

    convert_a<<<4096, 256, 0, stream>>>(disp, a_bf);
    convert_b1<<<dim3(E_, H_ / 64, N1 / 128), 256, 0, stream>>>(gup, b1t);
    gemm8p<0><<<2048, 512, 0, stream>>>(a_bf, b1t, gub, actb);
    convert_b2<<<dim3(E_, I_ / 64, H_ / 64), 256, 0, stream>>>(down, b2t);
    gemm8p<1><<<1024, 512, 0, stream>>>(actb, b2t, dbias, out);
}